// Round 1
// baseline (316.422 us; speedup 1.0000x reference)
//
#include <hip/hip_runtime.h>

#define BATCH 16
#define CH    512
#define NSP   1024
#define HIDD  2048

typedef __bf16 bf16x8 __attribute__((ext_vector_type(8)));
typedef float floatx4 __attribute__((ext_vector_type(4)));

__device__ __forceinline__ float bf2f(unsigned short u) {
    union { unsigned int i; float f; } v; v.i = ((unsigned int)u) << 16; return v.f;
}
__device__ __forceinline__ unsigned short f2bf(float f) {
    union { float f; unsigned int i; } v; v.f = f;
    unsigned int i = v.i;
    return (unsigned short)((i + 0x7FFFu + ((i >> 16) & 1u)) >> 16);
}

// async global->LDS, 16B per lane; LDS dst is wave-uniform base + lane*16
__device__ __forceinline__ void gload16(const void* g, void* l) {
    __builtin_amdgcn_global_load_lds(
        (__attribute__((address_space(1))) unsigned int*)(g),
        (__attribute__((address_space(3))) unsigned int*)(l),
        16, 0, 0);
}

// ---------------------------------------------------------------------------
// C = A (MxK, row-major) * B^T  where Bm is (NxK, row-major). K inner for both.
// 128x128 block tile, BK=32, 4 waves, each wave 64x64 via 4x4 mfma 16x16x32.
// EPI: 0 = scale -> bf16 ; 1 = plain -> bf16 ; 2 = +bias,relu -> bf16 ;
//      3 = +bias -> fp32
// ---------------------------------------------------------------------------
template<int EPI>
__global__ __launch_bounds__(256)
void gemm_bt(const unsigned short* __restrict__ A,
             const unsigned short* __restrict__ Bm,
             void* __restrict__ Cout,
             int M, int Nn, int K,
             long sAb, long sBb, long sCb,
             const float* __restrict__ bias, float scale)
{
    __shared__ unsigned short sA[128 * 32];   // [m][k] 64B rows
    __shared__ unsigned short sB[128 * 32];   // [n][k] 64B rows

    const int tid  = threadIdx.x;
    const int lane = tid & 63;
    const int w    = tid >> 6;        // wave 0..3
    const int quad = lane >> 4;
    const int l15  = lane & 15;
    const int mw   = (w >> 1) * 64;   // wave's m offset in tile
    const int nw   = (w & 1) * 64;    // wave's n offset in tile

    const int m0 = blockIdx.y * 128;
    const int n0 = blockIdx.x * 128;
    const int b  = blockIdx.z;

    A  += (size_t)b * sAb;
    Bm += (size_t)b * sBb;

    // staging pointers: wave w covers rows [w*32, w*32+32) of each tile.
    const unsigned short* pA = A  + (size_t)(m0 + w * 32 + (lane >> 2)) * K + (lane & 3) * 8;
    const unsigned short* pB = Bm + (size_t)(n0 + w * 32 + (lane >> 2)) * K + (lane & 3) * 8;
    unsigned short* sAw = sA + w * 1024;
    unsigned short* sBw = sB + w * 1024;
    const size_t rowskip = (size_t)16 * K;

    floatx4 acc[4][4];
#pragma unroll
    for (int i = 0; i < 4; i++)
#pragma unroll
        for (int j = 0; j < 4; j++) acc[i][j] = (floatx4){0.f, 0.f, 0.f, 0.f};

    const unsigned short* aBase = sA + (mw + l15) * 32 + quad * 8;
    const unsigned short* bBase = sB + (nw + l15) * 32 + quad * 8;

    for (int k0 = 0; k0 < K; k0 += 32) {
        gload16(pA,           sAw);
        gload16(pA + rowskip, sAw + 512);
        gload16(pB,           sBw);
        gload16(pB + rowskip, sBw + 512);
        pA += 32; pB += 32;
        __syncthreads();   // drains vmcnt(0): LDS tiles complete + visible

        bf16x8 af[4], bfr[4];
#pragma unroll
        for (int mi = 0; mi < 4; mi++) af[mi]  = *(const bf16x8*)(aBase + mi * 512);
#pragma unroll
        for (int ni = 0; ni < 4; ni++) bfr[ni] = *(const bf16x8*)(bBase + ni * 512);
#pragma unroll
        for (int mi = 0; mi < 4; mi++)
#pragma unroll
            for (int ni = 0; ni < 4; ni++)
                acc[mi][ni] = __builtin_amdgcn_mfma_f32_16x16x32_bf16(
                    af[mi], bfr[ni], acc[mi][ni], 0, 0, 0);
        __syncthreads();   // all waves done reading before next stage overwrites
    }

    // epilogue: D row = quad*4 + reg, col = lane&15  (m89/m91-verified layout)
    if constexpr (EPI == 3) {
        float* Cf = (float*)Cout + (size_t)b * sCb;
#pragma unroll
        for (int ni = 0; ni < 4; ni++) {
            const int n = n0 + nw + ni * 16 + l15;
            const float bv = bias[n];
#pragma unroll
            for (int mi = 0; mi < 4; mi++) {
                const int mbase = m0 + mw + mi * 16 + quad * 4;
#pragma unroll
                for (int r = 0; r < 4; r++)
                    Cf[(size_t)(mbase + r) * Nn + n] = acc[mi][ni][r] + bv;
            }
        }
    } else {
        unsigned short* Cb = (unsigned short*)Cout + (size_t)b * sCb;
#pragma unroll
        for (int ni = 0; ni < 4; ni++) {
            const int n = n0 + nw + ni * 16 + l15;
            float bv = 0.f;
            if constexpr (EPI == 2) bv = bias[n];
#pragma unroll
            for (int mi = 0; mi < 4; mi++) {
                const int mbase = m0 + mw + mi * 16 + quad * 4;
#pragma unroll
                for (int r = 0; r < 4; r++) {
                    float v = acc[mi][ni][r];
                    if constexpr (EPI == 0) v *= scale;
                    if constexpr (EPI == 2) v = fmaxf(v + bv, 0.f);
                    Cb[(size_t)(mbase + r) * Nn + n] = f2bf(v);
                }
            }
        }
    }
}

// x [B][C][N] fp32 -> Xbf [B][C][N] bf16 and XT [B][N][C] bf16
__global__ __launch_bounds__(256)
void pack_x_kernel(const float* __restrict__ x,
                   unsigned short* __restrict__ Xbf,
                   unsigned short* __restrict__ XT)
{
    __shared__ float tile[32][33];
    const int tx = threadIdx.x, ty = threadIdx.y;
    const int n0 = blockIdx.x * 32, c0 = blockIdx.y * 32, b = blockIdx.z;
    const size_t base = (size_t)b * CH * NSP;
#pragma unroll
    for (int i = ty; i < 32; i += 8) {
        float v = x[base + (size_t)(c0 + i) * NSP + n0 + tx];
        tile[i][tx] = v;
        Xbf[base + (size_t)(c0 + i) * NSP + n0 + tx] = f2bf(v);
    }
    __syncthreads();
    const size_t tbase = (size_t)b * NSP * CH;
#pragma unroll
    for (int i = ty; i < 32; i += 8)
        XT[tbase + (size_t)(n0 + i) * CH + c0 + tx] = f2bf(tile[tx][i]);
}

__global__ __launch_bounds__(256)
void cast_bf16_kernel(const float* __restrict__ src,
                      unsigned short* __restrict__ dst, int n)
{
    int i = blockIdx.x * 256 + threadIdx.x;
    if (i < n) dst[i] = f2bf(src[i]);
}

// in-place row softmax on bf16 scores, rows of length NSP=1024
__global__ __launch_bounds__(256)
void softmax_kernel(unsigned short* __restrict__ S)
{
    const int row = blockIdx.x;
    unsigned short* p = S + (size_t)row * NSP;
    const int t = threadIdx.x;

    ushort4 u = ((const ushort4*)p)[t];
    float v0 = bf2f(u.x), v1 = bf2f(u.y), v2 = bf2f(u.z), v3 = bf2f(u.w);

    float m = fmaxf(fmaxf(v0, v1), fmaxf(v2, v3));
#pragma unroll
    for (int off = 32; off > 0; off >>= 1) m = fmaxf(m, __shfl_xor(m, off));
    __shared__ float redmax[4], redsum[4];
    const int wid = t >> 6;
    if ((t & 63) == 0) redmax[wid] = m;
    __syncthreads();
    m = fmaxf(fmaxf(redmax[0], redmax[1]), fmaxf(redmax[2], redmax[3]));

    v0 = __expf(v0 - m); v1 = __expf(v1 - m);
    v2 = __expf(v2 - m); v3 = __expf(v3 - m);
    float s = v0 + v1 + v2 + v3;
#pragma unroll
    for (int off = 32; off > 0; off >>= 1) s += __shfl_xor(s, off);
    if ((t & 63) == 0) redsum[wid] = s;
    __syncthreads();
    s = redsum[0] + redsum[1] + redsum[2] + redsum[3];

    const float inv = 1.0f / s;
    ushort4 o;
    o.x = f2bf(v0 * inv); o.y = f2bf(v1 * inv);
    o.z = f2bf(v2 * inv); o.w = f2bf(v3 * inv);
    ((ushort4*)p)[t] = o;
}

// out[b][c][n] = Y[b][n][c] + x[b][c][n]
__global__ __launch_bounds__(256)
void finalize_kernel(const float* __restrict__ Y,
                     const float* __restrict__ x,
                     float* __restrict__ out)
{
    __shared__ float tile[32][33];
    const int tx = threadIdx.x, ty = threadIdx.y;
    const int c0 = blockIdx.x * 32, n0 = blockIdx.y * 32, b = blockIdx.z;
    const size_t ybase = (size_t)b * NSP * CH;
#pragma unroll
    for (int i = ty; i < 32; i += 8)
        tile[i][tx] = Y[ybase + (size_t)(n0 + i) * CH + c0 + tx];
    __syncthreads();
    const size_t xbase = (size_t)b * CH * NSP;
#pragma unroll
    for (int i = ty; i < 32; i += 8) {
        const int c = c0 + i, n = n0 + tx;
        out[xbase + (size_t)c * NSP + n] = tile[tx][i] + x[xbase + (size_t)c * NSP + n];
    }
}

extern "C" void kernel_launch(void* const* d_in, const int* in_sizes, int n_in,
                              void* d_out, int out_size, void* d_ws, size_t ws_size,
                              hipStream_t stream)
{
    const float* x  = (const float*)d_in[0];
    const float* w1 = (const float*)d_in[1];
    const float* b1 = (const float*)d_in[2];
    const float* w2 = (const float*)d_in[3];
    const float* b2 = (const float*)d_in[4];
    float* out = (float*)d_out;

    char* ws = (char*)d_ws;
    unsigned short* Xbf = (unsigned short*)ws; ws += (size_t)BATCH * CH * NSP * 2;   // 16 MB
    unsigned short* XT  = (unsigned short*)ws; ws += (size_t)BATCH * NSP * CH * 2;   // 16 MB
    unsigned short* W1b = (unsigned short*)ws; ws += (size_t)HIDD * CH * 2;          //  2 MB
    unsigned short* W2b = (unsigned short*)ws; ws += (size_t)CH * HIDD * 2;          //  2 MB
    unsigned short* P   = (unsigned short*)ws; ws += (size_t)BATCH * NSP * NSP * 2;  // 32 MB
    unsigned short* O   = (unsigned short*)ws; ws += (size_t)BATCH * NSP * CH * 2;   // 16 MB
    unsigned short* Hb  = (unsigned short*)ws; ws += (size_t)BATCH * NSP * HIDD * 2; // 64 MB
    float*          Y   = (float*)ws;          ws += (size_t)BATCH * NSP * CH * 4;   // 32 MB

    const dim3 blk(256);

    // pack inputs to bf16 (X and X^T), weights to bf16
    pack_x_kernel<<<dim3(NSP / 32, CH / 32, BATCH), dim3(32, 8), 0, stream>>>(x, Xbf, XT);
    cast_bf16_kernel<<<dim3((HIDD * CH) / 256), blk, 0, stream>>>(w1, W1b, HIDD * CH);
    cast_bf16_kernel<<<dim3((CH * HIDD) / 256), blk, 0, stream>>>(w2, W2b, CH * HIDD);

    // S = scale * XT * XT^T   (per batch)  -> bf16 scores in P
    gemm_bt<0><<<dim3(NSP / 128, NSP / 128, BATCH), blk, 0, stream>>>(
        XT, XT, P, NSP, NSP, CH,
        (long)NSP * CH, (long)NSP * CH, (long)NSP * NSP, nullptr, 0.04419417382415922f);

    // row softmax in place
    softmax_kernel<<<dim3(BATCH * NSP), blk, 0, stream>>>(P);

    // O = P * X^T  (B^T operand = Xbf [C][N])
    gemm_bt<1><<<dim3(CH / 128, NSP / 128, BATCH), blk, 0, stream>>>(
        P, Xbf, O, NSP, CH, NSP,
        (long)NSP * NSP, (long)CH * NSP, (long)NSP * CH, nullptr, 1.f);

    // H = relu(O * W1^T + b1)   (batches flattened into M)
    gemm_bt<2><<<dim3(HIDD / 128, (BATCH * NSP) / 128, 1), blk, 0, stream>>>(
        O, W1b, Hb, BATCH * NSP, HIDD, CH, 0, 0, 0, b1, 1.f);

    // Y = H * W2^T + b2  (fp32 out)
    gemm_bt<3><<<dim3(CH / 128, (BATCH * NSP) / 128, 1), blk, 0, stream>>>(
        Hb, W2b, Y, BATCH * NSP, CH, HIDD, 0, 0, 0, b2, 1.f);

    // out = Y^T + x
    finalize_kernel<<<dim3(CH / 32, NSP / 32, BATCH), dim3(32, 8), 0, stream>>>(Y, x, out);
}

// Round 2
// 314.380 us; speedup vs baseline: 1.0065x; 1.0065x over previous
//
#include <hip/hip_runtime.h>

#define BATCH 16
#define CH    512
#define NSP   1024
#define HIDD  2048

typedef __bf16 bf16x8 __attribute__((ext_vector_type(8)));
typedef float floatx4 __attribute__((ext_vector_type(4)));

__device__ __forceinline__ float bf2f(unsigned short u) {
    union { unsigned int i; float f; } v; v.i = ((unsigned int)u) << 16; return v.f;
}
__device__ __forceinline__ unsigned short f2bf(float f) {
    union { float f; unsigned int i; } v; v.f = f;
    unsigned int i = v.i;
    return (unsigned short)((i + 0x7FFFu + ((i >> 16) & 1u)) >> 16);
}

// async global->LDS, 16B per lane; LDS dst is wave-uniform base + lane*16
__device__ __forceinline__ void gload16(const void* g, void* l) {
    __builtin_amdgcn_global_load_lds(
        (__attribute__((address_space(1))) unsigned int*)(g),
        (__attribute__((address_space(3))) unsigned int*)(l),
        16, 0, 0);
}

// ---------------------------------------------------------------------------
// C = A (MxK, row-major) * B^T  where Bm is (NxK, row-major). K inner for both.
// 128x128 block tile, BK=64, 4 waves, each wave 64x64 via 4x4 mfma 16x16x32.
// LDS layout: per 8-row group, 16B granules are XOR-swizzled (g ^ (row&7))
// so ds_read_b128 fragment reads hit all 32 banks per 16-lane phase.
// EPI: 0 = scale -> bf16 ; 1 = plain -> bf16 ; 2 = +bias,relu -> bf16 ;
//      4 = transposed out: C[i][j] written to out[(j>>10)*CH*NSP + i*NSP +
//          (j&1023)] + bias[i] + resid[same]  (fp32)  -- used for Y^T=W2*H^T
// ---------------------------------------------------------------------------
template<int EPI>
__global__ __launch_bounds__(256)
void gemm_bt(const unsigned short* __restrict__ A,
             const unsigned short* __restrict__ Bm,
             void* __restrict__ Cout,
             int M, int Nn, int K,
             long sAb, long sBb, long sCb,
             const float* __restrict__ bias, float scale,
             const float* __restrict__ resid)
{
    __shared__ unsigned short sA[128 * 64];   // 16 KB, rows of 128B (8 granules)
    __shared__ unsigned short sB[128 * 64];

    const int tid  = threadIdx.x;
    const int lane = tid & 63;
    const int w    = tid >> 6;        // wave 0..3
    const int quad = lane >> 4;
    const int l15  = lane & 15;
    const int axor = l15 & 7;         // reader-side granule swizzle
    const int mw   = (w >> 1) * 64;   // wave's m offset in tile
    const int nw   = (w & 1) * 64;    // wave's n offset in tile

    const int m0 = blockIdx.y * 128;
    const int n0 = blockIdx.x * 128;
    const int b  = blockIdx.z;

    A  += (size_t)b * sAb;
    Bm += (size_t)b * sBb;

    // staging: wave w covers tile rows [w*32, w*32+32); load instr i covers
    // 8 rows (row = w*32 + i*8 + (lane>>3)). granule per lane is swizzled:
    const int srow = lane >> 3;               // 0..7
    const int sg   = (lane & 7) ^ srow;       // i-independent
    const unsigned short* pA = A  + (size_t)(m0 + w * 32 + srow) * K + sg * 8;
    const unsigned short* pB = Bm + (size_t)(n0 + w * 32 + srow) * K + sg * 8;
    unsigned short* sAw = sA + w * 2048;      // 32 rows * 64 shorts
    unsigned short* sBw = sB + w * 2048;
    const size_t rowskip = (size_t)8 * K;     // 8 rows per load instr

    floatx4 acc[4][4];
#pragma unroll
    for (int i = 0; i < 4; i++)
#pragma unroll
        for (int j = 0; j < 4; j++) acc[i][j] = (floatx4){0.f, 0.f, 0.f, 0.f};

    for (int k0 = 0; k0 < K; k0 += 64) {
        gload16(pA,               sAw);
        gload16(pA +     rowskip, sAw + 512);
        gload16(pA + 2 * rowskip, sAw + 1024);
        gload16(pA + 3 * rowskip, sAw + 1536);
        gload16(pB,               sBw);
        gload16(pB +     rowskip, sBw + 512);
        gload16(pB + 2 * rowskip, sBw + 1024);
        gload16(pB + 3 * rowskip, sBw + 1536);
        pA += 64; pB += 64;
        __syncthreads();   // drains vmcnt(0): LDS tiles complete + visible

#pragma unroll
        for (int ksub = 0; ksub < 2; ksub++) {
            bf16x8 af[4], bfr[4];
#pragma unroll
            for (int mi = 0; mi < 4; mi++)
                af[mi] = *(const bf16x8*)(sA + (mw + mi * 16 + l15) * 64
                                        + ((ksub * 4 + quad) ^ axor) * 8);
#pragma unroll
            for (int ni = 0; ni < 4; ni++)
                bfr[ni] = *(const bf16x8*)(sB + (nw + ni * 16 + l15) * 64
                                        + ((ksub * 4 + quad) ^ axor) * 8);
#pragma unroll
            for (int mi = 0; mi < 4; mi++)
#pragma unroll
                for (int ni = 0; ni < 4; ni++)
                    acc[mi][ni] = __builtin_amdgcn_mfma_f32_16x16x32_bf16(
                        af[mi], bfr[ni], acc[mi][ni], 0, 0, 0);
        }
        __syncthreads();   // all waves done reading before next stage overwrites
    }

    // epilogue: D row = quad*4 + reg, col = lane&15  (m89/m91-verified layout)
    if constexpr (EPI == 4) {
        float* Of = (float*)Cout;
#pragma unroll
        for (int ni = 0; ni < 4; ni++) {
            const int j  = n0 + nw + ni * 16 + l15;   // flattened (batch, n_sp)
            const int bb = j >> 10, ns = j & 1023;
            const size_t cbase = (size_t)bb * CH * NSP + ns;
#pragma unroll
            for (int mi = 0; mi < 4; mi++) {
                const int ibase = m0 + mw + mi * 16 + quad * 4;
#pragma unroll
                for (int r = 0; r < 4; r++) {
                    const int c = ibase + r;
                    const size_t a = cbase + (size_t)c * NSP;
                    Of[a] = acc[mi][ni][r] + bias[c] + resid[a];
                }
            }
        }
    } else {
        unsigned short* Cb = (unsigned short*)Cout + (size_t)b * sCb;
#pragma unroll
        for (int ni = 0; ni < 4; ni++) {
            const int n = n0 + nw + ni * 16 + l15;
            float bv = 0.f;
            if constexpr (EPI == 2) bv = bias[n];
#pragma unroll
            for (int mi = 0; mi < 4; mi++) {
                const int mbase = m0 + mw + mi * 16 + quad * 4;
#pragma unroll
                for (int r = 0; r < 4; r++) {
                    float v = acc[mi][ni][r];
                    if constexpr (EPI == 0) v *= scale;
                    if constexpr (EPI == 2) v = fmaxf(v + bv, 0.f);
                    Cb[(size_t)(mbase + r) * Nn + n] = f2bf(v);
                }
            }
        }
    }
}

// x [B][C][N] fp32 -> Xbf [B][C][N] bf16 and XT [B][N][C] bf16
__global__ __launch_bounds__(256)
void pack_x_kernel(const float* __restrict__ x,
                   unsigned short* __restrict__ Xbf,
                   unsigned short* __restrict__ XT)
{
    __shared__ float tile[32][33];
    const int tx = threadIdx.x, ty = threadIdx.y;
    const int n0 = blockIdx.x * 32, c0 = blockIdx.y * 32, b = blockIdx.z;
    const size_t base = (size_t)b * CH * NSP;
#pragma unroll
    for (int i = ty; i < 32; i += 8) {
        float v = x[base + (size_t)(c0 + i) * NSP + n0 + tx];
        tile[i][tx] = v;
        Xbf[base + (size_t)(c0 + i) * NSP + n0 + tx] = f2bf(v);
    }
    __syncthreads();
    const size_t tbase = (size_t)b * NSP * CH;
#pragma unroll
    for (int i = ty; i < 32; i += 8)
        XT[tbase + (size_t)(n0 + i) * CH + c0 + tx] = f2bf(tile[tx][i]);
}

__global__ __launch_bounds__(256)
void cast_bf16_kernel(const float* __restrict__ src,
                      unsigned short* __restrict__ dst, int n)
{
    int i = blockIdx.x * 256 + threadIdx.x;
    if (i < n) dst[i] = f2bf(src[i]);
}

// in-place row softmax on bf16 scores, rows of length NSP=1024
__global__ __launch_bounds__(256)
void softmax_kernel(unsigned short* __restrict__ S)
{
    const int row = blockIdx.x;
    unsigned short* p = S + (size_t)row * NSP;
    const int t = threadIdx.x;

    ushort4 u = ((const ushort4*)p)[t];
    float v0 = bf2f(u.x), v1 = bf2f(u.y), v2 = bf2f(u.z), v3 = bf2f(u.w);

    float m = fmaxf(fmaxf(v0, v1), fmaxf(v2, v3));
#pragma unroll
    for (int off = 32; off > 0; off >>= 1) m = fmaxf(m, __shfl_xor(m, off));
    __shared__ float redmax[4], redsum[4];
    const int wid = t >> 6;
    if ((t & 63) == 0) redmax[wid] = m;
    __syncthreads();
    m = fmaxf(fmaxf(redmax[0], redmax[1]), fmaxf(redmax[2], redmax[3]));

    v0 = __expf(v0 - m); v1 = __expf(v1 - m);
    v2 = __expf(v2 - m); v3 = __expf(v3 - m);
    float s = v0 + v1 + v2 + v3;
#pragma unroll
    for (int off = 32; off > 0; off >>= 1) s += __shfl_xor(s, off);
    if ((t & 63) == 0) redsum[wid] = s;
    __syncthreads();
    s = redsum[0] + redsum[1] + redsum[2] + redsum[3];

    const float inv = 1.0f / s;
    ushort4 o;
    o.x = f2bf(v0 * inv); o.y = f2bf(v1 * inv);
    o.z = f2bf(v2 * inv); o.w = f2bf(v3 * inv);
    ((ushort4*)p)[t] = o;
}

extern "C" void kernel_launch(void* const* d_in, const int* in_sizes, int n_in,
                              void* d_out, int out_size, void* d_ws, size_t ws_size,
                              hipStream_t stream)
{
    const float* x  = (const float*)d_in[0];
    const float* w1 = (const float*)d_in[1];
    const float* b1 = (const float*)d_in[2];
    const float* w2 = (const float*)d_in[3];
    const float* b2 = (const float*)d_in[4];
    float* out = (float*)d_out;

    char* ws = (char*)d_ws;
    unsigned short* Xbf = (unsigned short*)ws; ws += (size_t)BATCH * CH * NSP * 2;   // 16 MB
    unsigned short* XT  = (unsigned short*)ws; ws += (size_t)BATCH * NSP * CH * 2;   // 16 MB
    unsigned short* W1b = (unsigned short*)ws; ws += (size_t)HIDD * CH * 2;          //  2 MB
    unsigned short* W2b = (unsigned short*)ws; ws += (size_t)CH * HIDD * 2;          //  2 MB
    unsigned short* P   = (unsigned short*)ws; ws += (size_t)BATCH * NSP * NSP * 2;  // 32 MB
    unsigned short* O   = (unsigned short*)ws; ws += (size_t)BATCH * NSP * CH * 2;   // 16 MB
    unsigned short* Hb  = (unsigned short*)ws; ws += (size_t)BATCH * NSP * HIDD * 2; // 64 MB

    const dim3 blk(256);

    // pack inputs to bf16 (X and X^T), weights to bf16
    pack_x_kernel<<<dim3(NSP / 32, CH / 32, BATCH), dim3(32, 8), 0, stream>>>(x, Xbf, XT);
    cast_bf16_kernel<<<dim3((HIDD * CH) / 256), blk, 0, stream>>>(w1, W1b, HIDD * CH);
    cast_bf16_kernel<<<dim3((CH * HIDD) / 256), blk, 0, stream>>>(w2, W2b, CH * HIDD);

    // S = scale * XT * XT^T   (per batch)  -> bf16 scores in P
    gemm_bt<0><<<dim3(NSP / 128, NSP / 128, BATCH), blk, 0, stream>>>(
        XT, XT, P, NSP, NSP, CH,
        (long)NSP * CH, (long)NSP * CH, (long)NSP * NSP, nullptr,
        0.04419417382415922f, nullptr);

    // row softmax in place
    softmax_kernel<<<dim3(BATCH * NSP), blk, 0, stream>>>(P);

    // O = P * X^T  (B^T operand = Xbf [C][N])
    gemm_bt<1><<<dim3(CH / 128, NSP / 128, BATCH), blk, 0, stream>>>(
        P, Xbf, O, NSP, CH, NSP,
        (long)NSP * NSP, (long)CH * NSP, (long)NSP * CH, nullptr, 1.f, nullptr);

    // H = relu(O * W1^T + b1)   (batches flattened into M)
    gemm_bt<2><<<dim3(HIDD / 128, (BATCH * NSP) / 128, 1), blk, 0, stream>>>(
        O, W1b, Hb, BATCH * NSP, HIDD, CH, 0, 0, 0, b1, 1.f, nullptr);

    // out = (W2 * H^T)[c][b*n] + b2[c] + x   — transposed epilogue, no
    // intermediate Y and no separate finalize pass
    gemm_bt<4><<<dim3((BATCH * NSP) / 128, CH / 128, 1), blk, 0, stream>>>(
        W2b, Hb, out, CH, BATCH * NSP, HIDD, 0, 0, 0, b2, 1.f, x);
}

// Round 3
// 296.655 us; speedup vs baseline: 1.0666x; 1.0597x over previous
//
#include <hip/hip_runtime.h>

#define BATCH 16
#define CH    512
#define NSP   1024
#define HIDD  2048

typedef __bf16 bf16x8 __attribute__((ext_vector_type(8)));
typedef float floatx4 __attribute__((ext_vector_type(4)));

__device__ __forceinline__ float bf2f(unsigned short u) {
    union { unsigned int i; float f; } v; v.i = ((unsigned int)u) << 16; return v.f;
}
__device__ __forceinline__ unsigned short f2bf(float f) {
    union { float f; unsigned int i; } v; v.f = f;
    unsigned int i = v.i;
    return (unsigned short)((i + 0x7FFFu + ((i >> 16) & 1u)) >> 16);
}

// async global->LDS, 16B per lane; LDS dst is wave-uniform base + lane*16
__device__ __forceinline__ void gload16(const void* g, void* l) {
    __builtin_amdgcn_global_load_lds(
        (__attribute__((address_space(1))) unsigned int*)(g),
        (__attribute__((address_space(3))) unsigned int*)(l),
        16, 0, 0);
}

// ---------------------------------------------------------------------------
// C = A (MxK, row-major) * B^T  where Bm is (NxK, row-major). K inner for both.
// 128x128 block tile, BK=32, 4 waves, each wave 64x64 via 4x4 mfma 16x16x32.
// Single-barrier LDS double-buffer: loads for tile k+1 issued right after the
// barrier that publishes tile k, so HBM/L2 latency overlaps compute.
// Bank swizzle (64B rows = 4 x 16B granules): LDS(row, s) holds global
// granule s ^ ((row>>1)&3); reader fetches granule quad via slot
// quad ^ ((l15>>1)&3) -> every 16-lane phase covers all 8 granule positions
// of the 128B bank period exactly twice = conflict-free (2-way is free).
// EPI: 0 = scale -> bf16 ; 1 = plain -> bf16 ; 2 = +bias,relu -> bf16 ;
//      4 = transposed out: C[i][j] -> out[(j>>10)*CH*NSP + i*NSP + (j&1023)]
//          + bias[i] + resid[same]  (fp32)   (used for Y^T = W2 * H^T)
// ---------------------------------------------------------------------------
template<int EPI>
__global__ __launch_bounds__(256, 4)
void gemm_bt(const unsigned short* __restrict__ A,
             const unsigned short* __restrict__ Bm,
             void* __restrict__ Cout,
             int M, int Nn, int K,
             long sAb, long sBb, long sCb,
             const float* __restrict__ bias, float scale,
             const float* __restrict__ resid)
{
    __shared__ unsigned short sA[2][128 * 32];   // 2 x 8 KB
    __shared__ unsigned short sB[2][128 * 32];

    const int tid  = threadIdx.x;
    const int lane = tid & 63;
    const int w    = tid >> 6;        // wave 0..3
    const int quad = lane >> 4;
    const int l15  = lane & 15;
    const int mw   = (w >> 1) * 64;   // wave's m offset in tile
    const int nw   = (w & 1) * 64;    // wave's n offset in tile

    const int m0 = blockIdx.y * 128;
    const int n0 = blockIdx.x * 128;
    const int b  = blockIdx.z;

    A  += (size_t)b * sAb;
    Bm += (size_t)b * sBb;

    // staging: wave w covers tile rows [w*32, w*32+32); each gload16 instr
    // fills 16 rows (lane>>2 = row, lane&3 = LDS granule slot). The global
    // granule fetched is swizzled so LDS(row,s) = global(row, s^((row>>1)&3)).
    const int srow = lane >> 2;                       // 0..15
    const int sg   = (lane & 3) ^ ((lane >> 3) & 3);  // swizzled global granule
    const unsigned short* pA = A  + (size_t)(m0 + w * 32 + srow) * K + sg * 8;
    const unsigned short* pB = Bm + (size_t)(n0 + w * 32 + srow) * K + sg * 8;
    const size_t rowskip16 = (size_t)16 * K;
    const int woff = w * 1024;        // wave's LDS base (32 rows * 32 shorts)

    floatx4 acc[4][4];
#pragma unroll
    for (int i = 0; i < 4; i++)
#pragma unroll
        for (int j = 0; j < 4; j++) acc[i][j] = (floatx4){0.f, 0.f, 0.f, 0.f};

    // reader granule slot (swizzle inverse)
    const int rslot = ((l15 >> 1) & 3);

    const int nIter = K >> 5;

    // prologue: stage tile 0 into buffer 0
    {
        unsigned short* dA = &sA[0][0] + woff;
        unsigned short* dB = &sB[0][0] + woff;
        gload16(pA,             dA);
        gload16(pA + rowskip16, dA + 512);
        gload16(pB,             dB);
        gload16(pB + rowskip16, dB + 512);
    }

    for (int it = 0; it < nIter; ++it) {
        __syncthreads();   // vmcnt(0) drain: tile 'it' resident in buf it&1

        if (it + 1 < nIter) {           // prefetch tile it+1 into other buffer
            const int koff = (it + 1) << 5;
            unsigned short* dA = &sA[(it + 1) & 1][0] + woff;
            unsigned short* dB = &sB[(it + 1) & 1][0] + woff;
            gload16(pA + koff,             dA);
            gload16(pA + koff + rowskip16, dA + 512);
            gload16(pB + koff,             dB);
            gload16(pB + koff + rowskip16, dB + 512);
        }

        const unsigned short* bufA = &sA[it & 1][0];
        const unsigned short* bufB = &sB[it & 1][0];
        bf16x8 af[4], bfr[4];
#pragma unroll
        for (int mi = 0; mi < 4; mi++)
            af[mi] = *(const bf16x8*)(bufA + (mw + mi * 16 + l15) * 32
                                      + (quad ^ rslot) * 8);
#pragma unroll
        for (int ni = 0; ni < 4; ni++)
            bfr[ni] = *(const bf16x8*)(bufB + (nw + ni * 16 + l15) * 32
                                       + (quad ^ rslot) * 8);
#pragma unroll
        for (int mi = 0; mi < 4; mi++)
#pragma unroll
            for (int ni = 0; ni < 4; ni++)
                acc[mi][ni] = __builtin_amdgcn_mfma_f32_16x16x32_bf16(
                    af[mi], bfr[ni], acc[mi][ni], 0, 0, 0);
        // no trailing barrier: next iteration's barrier provides the
        // read-before-overwrite guarantee (overwrite of buf it&1 is only
        // issued after the barrier at iteration it+1).
    }

    // epilogue: D row = quad*4 + reg, col = lane&15  (m89/m91-verified layout)
    if constexpr (EPI == 4) {
        float* Of = (float*)Cout;
#pragma unroll
        for (int ni = 0; ni < 4; ni++) {
            const int j  = n0 + nw + ni * 16 + l15;   // flattened (batch, n_sp)
            const int bb = j >> 10, ns = j & 1023;
            const size_t cbase = (size_t)bb * CH * NSP + ns;
#pragma unroll
            for (int mi = 0; mi < 4; mi++) {
                const int ibase = m0 + mw + mi * 16 + quad * 4;
#pragma unroll
                for (int r = 0; r < 4; r++) {
                    const int c = ibase + r;
                    const size_t a = cbase + (size_t)c * NSP;
                    Of[a] = acc[mi][ni][r] + bias[c] + resid[a];
                }
            }
        }
    } else {
        unsigned short* Cb = (unsigned short*)Cout + (size_t)b * sCb;
#pragma unroll
        for (int ni = 0; ni < 4; ni++) {
            const int n = n0 + nw + ni * 16 + l15;
            float bv = 0.f;
            if constexpr (EPI == 2) bv = bias[n];
#pragma unroll
            for (int mi = 0; mi < 4; mi++) {
                const int mbase = m0 + mw + mi * 16 + quad * 4;
#pragma unroll
                for (int r = 0; r < 4; r++) {
                    float v = acc[mi][ni][r];
                    if constexpr (EPI == 0) v *= scale;
                    if constexpr (EPI == 2) v = fmaxf(v + bv, 0.f);
                    Cb[(size_t)(mbase + r) * Nn + n] = f2bf(v);
                }
            }
        }
    }
}

// x [B][C][N] fp32 -> Xbf [B][C][N] bf16 and XT [B][N][C] bf16
__global__ __launch_bounds__(256)
void pack_x_kernel(const float* __restrict__ x,
                   unsigned short* __restrict__ Xbf,
                   unsigned short* __restrict__ XT)
{
    __shared__ float tile[32][33];
    const int tx = threadIdx.x, ty = threadIdx.y;
    const int n0 = blockIdx.x * 32, c0 = blockIdx.y * 32, b = blockIdx.z;
    const size_t base = (size_t)b * CH * NSP;
#pragma unroll
    for (int i = ty; i < 32; i += 8) {
        float v = x[base + (size_t)(c0 + i) * NSP + n0 + tx];
        tile[i][tx] = v;
        Xbf[base + (size_t)(c0 + i) * NSP + n0 + tx] = f2bf(v);
    }
    __syncthreads();
    const size_t tbase = (size_t)b * NSP * CH;
#pragma unroll
    for (int i = ty; i < 32; i += 8)
        XT[tbase + (size_t)(n0 + i) * CH + c0 + tx] = f2bf(tile[tx][i]);
}

__global__ __launch_bounds__(256)
void cast_bf16_kernel(const float* __restrict__ src,
                      unsigned short* __restrict__ dst, int n)
{
    int i = blockIdx.x * 256 + threadIdx.x;
    if (i < n) dst[i] = f2bf(src[i]);
}

// in-place row softmax on bf16 scores, rows of length NSP=1024
__global__ __launch_bounds__(256)
void softmax_kernel(unsigned short* __restrict__ S)
{
    const int row = blockIdx.x;
    unsigned short* p = S + (size_t)row * NSP;
    const int t = threadIdx.x;

    ushort4 u = ((const ushort4*)p)[t];
    float v0 = bf2f(u.x), v1 = bf2f(u.y), v2 = bf2f(u.z), v3 = bf2f(u.w);

    float m = fmaxf(fmaxf(v0, v1), fmaxf(v2, v3));
#pragma unroll
    for (int off = 32; off > 0; off >>= 1) m = fmaxf(m, __shfl_xor(m, off));
    __shared__ float redmax[4], redsum[4];
    const int wid = t >> 6;
    if ((t & 63) == 0) redmax[wid] = m;
    __syncthreads();
    m = fmaxf(fmaxf(redmax[0], redmax[1]), fmaxf(redmax[2], redmax[3]));

    v0 = __expf(v0 - m); v1 = __expf(v1 - m);
    v2 = __expf(v2 - m); v3 = __expf(v3 - m);
    float s = v0 + v1 + v2 + v3;
#pragma unroll
    for (int off = 32; off > 0; off >>= 1) s += __shfl_xor(s, off);
    if ((t & 63) == 0) redsum[wid] = s;
    __syncthreads();
    s = redsum[0] + redsum[1] + redsum[2] + redsum[3];

    const float inv = 1.0f / s;
    ushort4 o;
    o.x = f2bf(v0 * inv); o.y = f2bf(v1 * inv);
    o.z = f2bf(v2 * inv); o.w = f2bf(v3 * inv);
    ((ushort4*)p)[t] = o;
}

extern "C" void kernel_launch(void* const* d_in, const int* in_sizes, int n_in,
                              void* d_out, int out_size, void* d_ws, size_t ws_size,
                              hipStream_t stream)
{
    const float* x  = (const float*)d_in[0];
    const float* w1 = (const float*)d_in[1];
    const float* b1 = (const float*)d_in[2];
    const float* w2 = (const float*)d_in[3];
    const float* b2 = (const float*)d_in[4];
    float* out = (float*)d_out;

    char* ws = (char*)d_ws;
    unsigned short* Xbf = (unsigned short*)ws; ws += (size_t)BATCH * CH * NSP * 2;   // 16 MB
    unsigned short* XT  = (unsigned short*)ws; ws += (size_t)BATCH * NSP * CH * 2;   // 16 MB
    unsigned short* W1b = (unsigned short*)ws; ws += (size_t)HIDD * CH * 2;          //  2 MB
    unsigned short* W2b = (unsigned short*)ws; ws += (size_t)CH * HIDD * 2;          //  2 MB
    unsigned short* P   = (unsigned short*)ws; ws += (size_t)BATCH * NSP * NSP * 2;  // 32 MB
    unsigned short* O   = (unsigned short*)ws; ws += (size_t)BATCH * NSP * CH * 2;   // 16 MB
    unsigned short* Hb  = (unsigned short*)ws; ws += (size_t)BATCH * NSP * HIDD * 2; // 64 MB

    const dim3 blk(256);

    // pack inputs to bf16 (X and X^T), weights to bf16
    pack_x_kernel<<<dim3(NSP / 32, CH / 32, BATCH), dim3(32, 8), 0, stream>>>(x, Xbf, XT);
    cast_bf16_kernel<<<dim3((HIDD * CH) / 256), blk, 0, stream>>>(w1, W1b, HIDD * CH);
    cast_bf16_kernel<<<dim3((CH * HIDD) / 256), blk, 0, stream>>>(w2, W2b, CH * HIDD);

    // S = scale * XT * XT^T   (per batch)  -> bf16 scores in P
    gemm_bt<0><<<dim3(NSP / 128, NSP / 128, BATCH), blk, 0, stream>>>(
        XT, XT, P, NSP, NSP, CH,
        (long)NSP * CH, (long)NSP * CH, (long)NSP * NSP, nullptr,
        0.04419417382415922f, nullptr);

    // row softmax in place
    softmax_kernel<<<dim3(BATCH * NSP), blk, 0, stream>>>(P);

    // O = P * X^T  (B^T operand = Xbf [C][N])
    gemm_bt<1><<<dim3(CH / 128, NSP / 128, BATCH), blk, 0, stream>>>(
        P, Xbf, O, NSP, CH, NSP,
        (long)NSP * NSP, (long)CH * NSP, (long)NSP * CH, nullptr, 1.f, nullptr);

    // H = relu(O * W1^T + b1)   (batches flattened into M)
    gemm_bt<2><<<dim3(HIDD / 128, (BATCH * NSP) / 128, 1), blk, 0, stream>>>(
        O, W1b, Hb, BATCH * NSP, HIDD, CH, 0, 0, 0, b1, 1.f, nullptr);

    // out = (W2 * H^T)[c][b*n] + b2[c] + x   — transposed epilogue, no
    // intermediate Y and no separate finalize pass
    gemm_bt<4><<<dim3((BATCH * NSP) / 128, CH / 128, 1), blk, 0, stream>>>(
        W2b, Hb, out, CH, BATCH * NSP, HIDD, 0, 0, 0, b2, 1.f, x);
}

// Round 4
// 282.229 us; speedup vs baseline: 1.1212x; 1.0511x over previous
//
#include <hip/hip_runtime.h>

#define BATCH 16
#define CH    512
#define NSP   1024
#define HIDD  2048

typedef __bf16 bf16x8 __attribute__((ext_vector_type(8)));
typedef float floatx4 __attribute__((ext_vector_type(4)));

__device__ __forceinline__ float bf2f(unsigned short u) {
    union { unsigned int i; float f; } v; v.i = ((unsigned int)u) << 16; return v.f;
}
__device__ __forceinline__ unsigned short f2bf(float f) {
    union { float f; unsigned int i; } v; v.f = f;
    unsigned int i = v.i;
    return (unsigned short)((i + 0x7FFFu + ((i >> 16) & 1u)) >> 16);
}

// async global->LDS, 16B per lane; LDS dst is wave-uniform base + lane*16
__device__ __forceinline__ void gload16(const void* g, void* l) {
    __builtin_amdgcn_global_load_lds(
        (__attribute__((address_space(1))) unsigned int*)(g),
        (__attribute__((address_space(3))) unsigned int*)(l),
        16, 0, 0);
}

// ---------------------------------------------------------------------------
// C = A (MxK, row-major) * B^T  (Bm is NxK row-major). 128x128 tile, BK=32,
// 4 waves, 4x4 mfma 16x16x32 per wave. Single-barrier LDS double-buffer.
// XOR bank swizzle on 16B granules (writer (lane&3)^((lane>>3)&3), reader
// quad^((l15>>1)&3)) -> 0 LDS bank conflicts (verified r2).
//
// MAP: XCD-aware block remap (flat 1-D grid, XCD = F % 8 round-robin):
//  0 scores: XCD owns 2 batches  (XT slabs L2-resident)
//  1 PV:     XCD owns 2 batches  (Xbf slab resident, P streamed 4x reuse)
//  2 FFN1:   XCD owns 16-m-stripe x all n (A-stripe 2MB + W1 2MB = L2)
//  3 out:    XCD owns 16 n-tiles x all m  (W2 2MB resident, H 4x reuse)
// EPI: 0 scale->bf16 ; 1 plain->bf16 ; 2 +bias,relu->bf16 ;
//      4 transposed fp32: C[i][j] -> out[(j>>10)*CH*NSP + i*NSP + (j&1023)]
//         + bias[i] + resid[same]
// ---------------------------------------------------------------------------
template<int EPI, int MAP>
__global__ __launch_bounds__(256, 4)
void gemm_bt(const unsigned short* __restrict__ A,
             const unsigned short* __restrict__ Bm,
             void* __restrict__ Cout,
             int Nn, int K,
             long sAb, long sBb, long sCb,
             const float* __restrict__ bias, float scale,
             const float* __restrict__ resid)
{
    __shared__ unsigned short sA[2][128 * 32];   // 2 x 8 KB
    __shared__ unsigned short sB[2][128 * 32];

    const int tid  = threadIdx.x;
    const int lane = tid & 63;
    const int w    = tid >> 6;        // wave 0..3
    const int quad = lane >> 4;
    const int l15  = lane & 15;
    const int mw   = (w >> 1) * 64;   // wave's m offset in tile
    const int nw   = (w & 1) * 64;    // wave's n offset in tile

    // XCD-aware decode of flat block id (XCD = F & 7 round-robin)
    const int F = blockIdx.x;
    int m0, n0, b;
    if constexpr (MAP == 0) {        // 1024 blocks: 2 batches/XCD, 8x8 tiles
        const int xcd = F & 7, s = F >> 3;
        b = xcd + ((s >> 6) << 3);
        const int j = s & 63; m0 = (j >> 3) << 7; n0 = (j & 7) << 7;
    } else if constexpr (MAP == 1) { // 512 blocks: 2 batches/XCD, 8x4 tiles
        const int xcd = F & 7, s = F >> 3;
        b = xcd + ((s >> 5) << 3);
        const int j = s & 31; m0 = (j >> 2) << 7; n0 = (j & 3) << 7;
    } else if constexpr (MAP == 2) { // 2048 blocks: 16-m-stripe/XCD x 16 n
        const int xcd = F & 7, s = F >> 3;
        b = 0; m0 = ((xcd << 4) + (s >> 4)) << 7; n0 = (s & 15) << 7;
    } else {                         // 512 blocks: 16 n-tiles/XCD x 4 m
        const int xcd = F & 7, s = F >> 3;
        b = 0; m0 = (s & 3) << 7; n0 = ((xcd << 4) + (s >> 2)) << 7;
    }

    A  += (size_t)b * sAb;
    Bm += (size_t)b * sBb;

    // staging: wave w covers tile rows [w*32, w*32+32); each gload16 instr
    // fills 16 rows (lane>>2 = row, lane&3 = LDS granule slot). The global
    // granule fetched is swizzled so LDS(row,s) = global(row, s^((row>>1)&3)).
    const int srow = lane >> 2;                       // 0..15
    const int sg   = (lane & 3) ^ ((lane >> 3) & 3);  // swizzled global granule
    const unsigned short* pA = A  + (size_t)(m0 + w * 32 + srow) * K + sg * 8;
    const unsigned short* pB = Bm + (size_t)(n0 + w * 32 + srow) * K + sg * 8;
    const size_t rowskip16 = (size_t)16 * K;
    const int woff = w * 1024;        // wave's LDS base (32 rows * 32 shorts)

    floatx4 acc[4][4];
#pragma unroll
    for (int i = 0; i < 4; i++)
#pragma unroll
        for (int j = 0; j < 4; j++) acc[i][j] = (floatx4){0.f, 0.f, 0.f, 0.f};

    // reader granule slot (swizzle inverse)
    const int rslot = ((l15 >> 1) & 3);

    const int nIter = K >> 5;

    // prologue: stage tile 0 into buffer 0
    {
        unsigned short* dA = &sA[0][0] + woff;
        unsigned short* dB = &sB[0][0] + woff;
        gload16(pA,             dA);
        gload16(pA + rowskip16, dA + 512);
        gload16(pB,             dB);
        gload16(pB + rowskip16, dB + 512);
    }

    for (int it = 0; it < nIter; ++it) {
        __syncthreads();   // vmcnt(0) drain: tile 'it' resident in buf it&1

        if (it + 1 < nIter) {           // prefetch tile it+1 into other buffer
            const int koff = (it + 1) << 5;
            unsigned short* dA = &sA[(it + 1) & 1][0] + woff;
            unsigned short* dB = &sB[(it + 1) & 1][0] + woff;
            gload16(pA + koff,             dA);
            gload16(pA + koff + rowskip16, dA + 512);
            gload16(pB + koff,             dB);
            gload16(pB + koff + rowskip16, dB + 512);
        }

        const unsigned short* bufA = &sA[it & 1][0];
        const unsigned short* bufB = &sB[it & 1][0];
        bf16x8 af[4], bfr[4];
#pragma unroll
        for (int mi = 0; mi < 4; mi++)
            af[mi] = *(const bf16x8*)(bufA + (mw + mi * 16 + l15) * 32
                                      + (quad ^ rslot) * 8);
#pragma unroll
        for (int ni = 0; ni < 4; ni++)
            bfr[ni] = *(const bf16x8*)(bufB + (nw + ni * 16 + l15) * 32
                                       + (quad ^ rslot) * 8);
#pragma unroll
        for (int mi = 0; mi < 4; mi++)
#pragma unroll
            for (int ni = 0; ni < 4; ni++)
                acc[mi][ni] = __builtin_amdgcn_mfma_f32_16x16x32_bf16(
                    af[mi], bfr[ni], acc[mi][ni], 0, 0, 0);
        // next iteration's barrier provides read-before-overwrite guarantee
    }

    // epilogue: D row = quad*4 + reg, col = lane&15  (m89/m91-verified layout)
    if constexpr (EPI == 4) {
        float* Of = (float*)Cout;
#pragma unroll
        for (int ni = 0; ni < 4; ni++) {
            const int j  = n0 + nw + ni * 16 + l15;   // flattened (batch, n_sp)
            const int bb = j >> 10, ns = j & 1023;
            const size_t cbase = (size_t)bb * CH * NSP + ns;
#pragma unroll
            for (int mi = 0; mi < 4; mi++) {
                const int ibase = m0 + mw + mi * 16 + quad * 4;
#pragma unroll
                for (int r = 0; r < 4; r++) {
                    const int c = ibase + r;
                    const size_t a = cbase + (size_t)c * NSP;
                    Of[a] = acc[mi][ni][r] + bias[c] + resid[a];
                }
            }
        }
    } else {
        unsigned short* Cb = (unsigned short*)Cout + (size_t)b * sCb;
#pragma unroll
        for (int ni = 0; ni < 4; ni++) {
            const int n = n0 + nw + ni * 16 + l15;
            float bv = 0.f;
            if constexpr (EPI == 2) bv = bias[n];
#pragma unroll
            for (int mi = 0; mi < 4; mi++) {
                const int mbase = m0 + mw + mi * 16 + quad * 4;
#pragma unroll
                for (int r = 0; r < 4; r++) {
                    float v = acc[mi][ni][r];
                    if constexpr (EPI == 0) v *= scale;
                    if constexpr (EPI == 2) v = fmaxf(v + bv, 0.f);
                    Cb[(size_t)(mbase + r) * Nn + n] = f2bf(v);
                }
            }
        }
    }
}

// x [B][C][N] fp32 -> Xbf [B][C][N] bf16 and XT [B][N][C] bf16
__global__ __launch_bounds__(256)
void pack_x_kernel(const float* __restrict__ x,
                   unsigned short* __restrict__ Xbf,
                   unsigned short* __restrict__ XT)
{
    __shared__ float tile[32][33];
    const int tx = threadIdx.x, ty = threadIdx.y;
    const int n0 = blockIdx.x * 32, c0 = blockIdx.y * 32, b = blockIdx.z;
    const size_t base = (size_t)b * CH * NSP;
#pragma unroll
    for (int i = ty; i < 32; i += 8) {
        float v = x[base + (size_t)(c0 + i) * NSP + n0 + tx];
        tile[i][tx] = v;
        Xbf[base + (size_t)(c0 + i) * NSP + n0 + tx] = f2bf(v);
    }
    __syncthreads();
    const size_t tbase = (size_t)b * NSP * CH;
#pragma unroll
    for (int i = ty; i < 32; i += 8)
        XT[tbase + (size_t)(n0 + i) * CH + c0 + tx] = f2bf(tile[tx][i]);
}

__global__ __launch_bounds__(256)
void cast_bf16_kernel(const float* __restrict__ src,
                      unsigned short* __restrict__ dst, int n)
{
    int i = blockIdx.x * 256 + threadIdx.x;
    if (i < n) dst[i] = f2bf(src[i]);
}

// in-place row softmax on bf16 scores, rows of length NSP=1024
__global__ __launch_bounds__(256)
void softmax_kernel(unsigned short* __restrict__ S)
{
    const int row = blockIdx.x;
    unsigned short* p = S + (size_t)row * NSP;
    const int t = threadIdx.x;

    ushort4 u = ((const ushort4*)p)[t];
    float v0 = bf2f(u.x), v1 = bf2f(u.y), v2 = bf2f(u.z), v3 = bf2f(u.w);

    float m = fmaxf(fmaxf(v0, v1), fmaxf(v2, v3));
#pragma unroll
    for (int off = 32; off > 0; off >>= 1) m = fmaxf(m, __shfl_xor(m, off));
    __shared__ float redmax[4], redsum[4];
    const int wid = t >> 6;
    if ((t & 63) == 0) redmax[wid] = m;
    __syncthreads();
    m = fmaxf(fmaxf(redmax[0], redmax[1]), fmaxf(redmax[2], redmax[3]));

    v0 = __expf(v0 - m); v1 = __expf(v1 - m);
    v2 = __expf(v2 - m); v3 = __expf(v3 - m);
    float s = v0 + v1 + v2 + v3;
#pragma unroll
    for (int off = 32; off > 0; off >>= 1) s += __shfl_xor(s, off);
    if ((t & 63) == 0) redsum[wid] = s;
    __syncthreads();
    s = redsum[0] + redsum[1] + redsum[2] + redsum[3];

    const float inv = 1.0f / s;
    ushort4 o;
    o.x = f2bf(v0 * inv); o.y = f2bf(v1 * inv);
    o.z = f2bf(v2 * inv); o.w = f2bf(v3 * inv);
    ((ushort4*)p)[t] = o;
}

extern "C" void kernel_launch(void* const* d_in, const int* in_sizes, int n_in,
                              void* d_out, int out_size, void* d_ws, size_t ws_size,
                              hipStream_t stream)
{
    const float* x  = (const float*)d_in[0];
    const float* w1 = (const float*)d_in[1];
    const float* b1 = (const float*)d_in[2];
    const float* w2 = (const float*)d_in[3];
    const float* b2 = (const float*)d_in[4];
    float* out = (float*)d_out;

    char* ws = (char*)d_ws;
    unsigned short* Xbf = (unsigned short*)ws; ws += (size_t)BATCH * CH * NSP * 2;   // 16 MB
    unsigned short* XT  = (unsigned short*)ws; ws += (size_t)BATCH * NSP * CH * 2;   // 16 MB
    unsigned short* W1b = (unsigned short*)ws; ws += (size_t)HIDD * CH * 2;          //  2 MB
    unsigned short* W2b = (unsigned short*)ws; ws += (size_t)CH * HIDD * 2;          //  2 MB
    unsigned short* P   = (unsigned short*)ws; ws += (size_t)BATCH * NSP * NSP * 2;  // 32 MB
    unsigned short* O   = (unsigned short*)ws; ws += (size_t)BATCH * NSP * CH * 2;   // 16 MB
    unsigned short* Hb  = (unsigned short*)ws; ws += (size_t)BATCH * NSP * HIDD * 2; // 64 MB

    const dim3 blk(256);

    // pack inputs to bf16 (X and X^T), weights to bf16
    pack_x_kernel<<<dim3(NSP / 32, CH / 32, BATCH), dim3(32, 8), 0, stream>>>(x, Xbf, XT);
    cast_bf16_kernel<<<dim3((HIDD * CH) / 256), blk, 0, stream>>>(w1, W1b, HIDD * CH);
    cast_bf16_kernel<<<dim3((CH * HIDD) / 256), blk, 0, stream>>>(w2, W2b, CH * HIDD);

    // S = scale * XT * XT^T   (per batch)  -> bf16 scores in P
    gemm_bt<0, 0><<<dim3(1024), blk, 0, stream>>>(
        XT, XT, P, NSP, CH,
        (long)NSP * CH, (long)NSP * CH, (long)NSP * NSP, nullptr,
        0.04419417382415922f, nullptr);

    // row softmax in place
    softmax_kernel<<<dim3(BATCH * NSP), blk, 0, stream>>>(P);

    // O = P * X^T  (B^T operand = Xbf [C][N])
    gemm_bt<1, 1><<<dim3(512), blk, 0, stream>>>(
        P, Xbf, O, CH, NSP,
        (long)NSP * NSP, (long)CH * NSP, (long)NSP * CH, nullptr, 1.f, nullptr);

    // H = relu(O * W1^T + b1)   (batches flattened into M)
    gemm_bt<2, 2><<<dim3(2048), blk, 0, stream>>>(
        O, W1b, Hb, HIDD, CH, 0, 0, 0, b1, 1.f, nullptr);

    // out = (W2 * H^T)[c][b*n] + b2[c] + x   — transposed epilogue
    gemm_bt<4, 3><<<dim3(512), blk, 0, stream>>>(
        W2b, Hb, out, BATCH * NSP, HIDD, 0, 0, 0, b2, 1.f, x);
}